// Round 1
// baseline (584.858 us; speedup 1.0000x reference)
//
#include <hip/hip_runtime.h>
#include <hip/hip_bf16.h>

typedef __bf16 bf16x8 __attribute__((ext_vector_type(8)));
typedef float f32x4 __attribute__((ext_vector_type(4)));

#define N_NODES 50000
#define NEDGE 160000

// out[i] = bias[i % 128], vectorized as float4
__global__ __launch_bounds__(256) void init_out_kernel(float* __restrict__ out,
                                                       const float* __restrict__ bias) {
    int i = blockIdx.x * 256 + threadIdx.x;  // float4 index
    float4 b = reinterpret_cast<const float4*>(bias)[i & 31];
    reinterpret_cast<float4*>(out)[i] = b;
}

// Compose W[r] = w_comp[r,0]*weight[0] + w_comp[r,1]*weight[1], store bf16 in
// MFMA B-fragment order: offset = (((r*8+n)*4+kk)*64+lane)*8 + j
// where element = W[r][k][o], k = kk*32 + (lane>>4)*8 + j, o = n*16 + (lane&15)
__global__ __launch_bounds__(256) void wfrag_kernel(const float* __restrict__ weight,
                                                    const float* __restrict__ wcomp,
                                                    __bf16* __restrict__ wfrag) {
    int tid = blockIdx.x * 256 + threadIdx.x;  // 65536 total
    int j    = tid & 7;
    int lane = (tid >> 3) & 63;
    int kk   = (tid >> 9) & 3;
    int n    = (tid >> 11) & 7;
    int r    = tid >> 14;
    int k = kk * 32 + ((lane >> 4) << 3) + j;
    int o = (n << 4) + (lane & 15);
    float v = wcomp[r * 2] * weight[k * 128 + o] +
              wcomp[r * 2 + 1] * weight[16384 + k * 128 + o];
    wfrag[tid] = (__bf16)v;
}

// H = x @ W_r  (M x 128, K=128), bf16 output. Block = 4 waves, 64 rows/block.
__global__ __launch_bounds__(256) void gemm_kernel(const float* __restrict__ x,
                                                   const __bf16* __restrict__ wfrag,
                                                   __bf16* __restrict__ H, int M) {
    __shared__ __bf16 wl[16384];  // 32 KB: [n][kk][lane][8]
    {
        const uint4* s = reinterpret_cast<const uint4*>(wfrag);
        uint4* d = reinterpret_cast<uint4*>(wl);
        int t = threadIdx.x;
#pragma unroll
        for (int i = 0; i < 8; ++i) d[t + i * 256] = s[t + i * 256];
    }
    __syncthreads();

    const int lane = threadIdx.x & 63;
    const int wave = threadIdx.x >> 6;
    const int g = lane >> 4;      // k sub-block
    const int m15 = lane & 15;    // A row / C col

    int row = blockIdx.x * 64 + wave * 16 + m15;
    int rowc = row < M ? row : M - 1;
    const float* xr = x + (size_t)rowc * 128 + g * 8;

    bf16x8 a[4];
#pragma unroll
    for (int kk = 0; kk < 4; ++kk) {
        float4 f0 = *reinterpret_cast<const float4*>(xr + kk * 32);
        float4 f1 = *reinterpret_cast<const float4*>(xr + kk * 32 + 4);
        bf16x8 t;
        t[0] = (__bf16)f0.x; t[1] = (__bf16)f0.y; t[2] = (__bf16)f0.z; t[3] = (__bf16)f0.w;
        t[4] = (__bf16)f1.x; t[5] = (__bf16)f1.y; t[6] = (__bf16)f1.z; t[7] = (__bf16)f1.w;
        a[kk] = t;
    }

    const bf16x8* wv = reinterpret_cast<const bf16x8*>(wl);
    f32x4 acc[8];
#pragma unroll
    for (int n = 0; n < 8; ++n) acc[n] = (f32x4){0.f, 0.f, 0.f, 0.f};

#pragma unroll
    for (int n = 0; n < 8; ++n) {
#pragma unroll
        for (int kk = 0; kk < 4; ++kk) {
            acc[n] = __builtin_amdgcn_mfma_f32_16x16x32_bf16(
                a[kk], wv[(n * 4 + kk) * 64 + lane], acc[n], 0, 0, 0);
        }
    }

    // C/D layout: col = lane&15, row = (lane>>4)*4 + reg
    int rowbase = blockIdx.x * 64 + wave * 16 + g * 4;
#pragma unroll
    for (int n = 0; n < 8; ++n) {
#pragma unroll
        for (int q = 0; q < 4; ++q) {
            int rr = rowbase + q;
            if (rr < M) H[(size_t)rr * 128 + n * 16 + m15] = (__bf16)acc[n][q];
        }
    }
}

// For each edge: out[dst] += H[src]  (64 lanes per edge, 2 feats per lane)
__global__ __launch_bounds__(256) void scatter_kernel(const __bf16* __restrict__ H,
                                                      const int* __restrict__ src,
                                                      const int* __restrict__ dst,
                                                      float* __restrict__ out) {
    int idx = blockIdx.x * 256 + threadIdx.x;
    int e = idx >> 6;
    int lane = idx & 63;
    int s = src[e];
    int d = dst[e];
    unsigned int hv = reinterpret_cast<const unsigned int*>(H)[(size_t)s * 64 + lane];
    union { unsigned int u; float f; } lo, hi;
    lo.u = hv << 16;           // element 2*lane   (low 16 bits)
    hi.u = hv & 0xFFFF0000u;   // element 2*lane+1 (high 16 bits)
    atomicAdd(&out[(size_t)d * 128 + lane * 2], lo.f);
    atomicAdd(&out[(size_t)d * 128 + lane * 2 + 1], hi.f);
}

extern "C" void kernel_launch(void* const* d_in, const int* in_sizes, int n_in,
                              void* d_out, int out_size, void* d_ws, size_t ws_size,
                              hipStream_t stream) {
    const float* x0     = (const float*)d_in[0];
    const float* x1     = (const float*)d_in[1];
    const float* weight = (const float*)d_in[2];
    const float* wcomp  = (const float*)d_in[3];
    const float* bias   = (const float*)d_in[4];
    const int* src[4] = {(const int*)d_in[5], (const int*)d_in[7],
                         (const int*)d_in[9], (const int*)d_in[11]};
    const int* dst[4] = {(const int*)d_in[6], (const int*)d_in[8],
                         (const int*)d_in[10], (const int*)d_in[12]};
    float* out = (float*)d_out;

    __bf16* wfrag = (__bf16*)d_ws;                       // 128 KB
    __bf16* H     = (__bf16*)((char*)d_ws + 131072);     // 12.8 MB, reused per rel

    // out = bias (also provides the zero-init for atomic accumulation)
    init_out_kernel<<<2 * N_NODES * 128 / 4 / 256, 256, 0, stream>>>(out, bias);
    wfrag_kernel<<<256, 256, 0, stream>>>(weight, wcomp, wfrag);

    const float* xs[4]  = {x0, x0, x1, x1};
    float* outs[4] = {out, out + (size_t)N_NODES * 128,
                      out, out + (size_t)N_NODES * 128};
    for (int r = 0; r < 4; ++r) {
        gemm_kernel<<<(N_NODES + 63) / 64, 256, 0, stream>>>(xs[r], wfrag + r * 16384, H, N_NODES);
        scatter_kernel<<<NEDGE * 64 / 256, 256, 0, stream>>>(H, src[r], dst[r], outs[r]);
    }
}

// Round 2
// 412.438 us; speedup vs baseline: 1.4180x; 1.4180x over previous
//
#include <hip/hip_runtime.h>
#include <hip/hip_bf16.h>

typedef __bf16 bf16x8 __attribute__((ext_vector_type(8)));
typedef float f32x4 __attribute__((ext_vector_type(4)));

#define N_NODES 50000
#define NEDGE 160000
#define CS 50048  // padded stride for counts/indptr/cursor arrays

// ---- workspace layout (bytes) ----
// wfrag:  0          .. 131072            (4 rel * 16384 bf16)
// HA:     131072     .. 12,931,072        (50000*128 bf16)
// HB:     12,931,072 .. 25,731,072
// counts: 25,731,072 .. +2*CS*4
// indptr: ...        .. +2*CS*4
// cursor: ...        .. +2*CS*4
// srcids: ...        .. +2*E*4
constexpr size_t OFF_WFRAG = 0;
constexpr size_t OFF_HA    = 131072;
constexpr size_t OFF_HB    = OFF_HA + 12800000;
constexpr size_t OFF_CNT   = OFF_HB + 12800000;
constexpr size_t OFF_IPTR  = OFF_CNT + (size_t)2 * CS * 4;
constexpr size_t OFF_CUR   = OFF_IPTR + (size_t)2 * CS * 4;
constexpr size_t OFF_SRC   = OFF_CUR + (size_t)2 * CS * 4;

// Compose W[r] = w_comp[r,0]*weight[0] + w_comp[r,1]*weight[1], store bf16 in
// MFMA B-fragment order: offset = (((r*8+n)*4+kk)*64+lane)*8 + j
// where element = W[r][k][o], k = kk*32 + (lane>>4)*8 + j, o = n*16 + (lane&15)
__global__ __launch_bounds__(256) void wfrag_kernel(const float* __restrict__ weight,
                                                    const float* __restrict__ wcomp,
                                                    __bf16* __restrict__ wfrag) {
    int tid = blockIdx.x * 256 + threadIdx.x;  // 65536 total
    int j    = tid & 7;
    int lane = (tid >> 3) & 63;
    int kk   = (tid >> 9) & 3;
    int n    = (tid >> 11) & 7;
    int r    = tid >> 14;
    int k = kk * 32 + ((lane >> 4) << 3) + j;
    int o = (n << 4) + (lane & 15);
    float v = wcomp[r * 2] * weight[k * 128 + o] +
              wcomp[r * 2 + 1] * weight[16384 + k * 128 + o];
    wfrag[tid] = (__bf16)v;
}

// H = x @ W_r  (M x 128, K=128), bf16 output. Block = 4 waves, 64 rows/block.
__global__ __launch_bounds__(256) void gemm_kernel(const float* __restrict__ x,
                                                   const __bf16* __restrict__ wfrag,
                                                   __bf16* __restrict__ H, int M) {
    __shared__ __bf16 wl[16384];  // 32 KB: [n][kk][lane][8]
    {
        const uint4* s = reinterpret_cast<const uint4*>(wfrag);
        uint4* d = reinterpret_cast<uint4*>(wl);
        int t = threadIdx.x;
#pragma unroll
        for (int i = 0; i < 8; ++i) d[t + i * 256] = s[t + i * 256];
    }
    __syncthreads();

    const int lane = threadIdx.x & 63;
    const int wave = threadIdx.x >> 6;
    const int g = lane >> 4;      // k sub-block
    const int m15 = lane & 15;    // A row / C col

    int row = blockIdx.x * 64 + wave * 16 + m15;
    int rowc = row < M ? row : M - 1;
    const float* xr = x + (size_t)rowc * 128 + g * 8;

    bf16x8 a[4];
#pragma unroll
    for (int kk = 0; kk < 4; ++kk) {
        float4 f0 = *reinterpret_cast<const float4*>(xr + kk * 32);
        float4 f1 = *reinterpret_cast<const float4*>(xr + kk * 32 + 4);
        bf16x8 t;
        t[0] = (__bf16)f0.x; t[1] = (__bf16)f0.y; t[2] = (__bf16)f0.z; t[3] = (__bf16)f0.w;
        t[4] = (__bf16)f1.x; t[5] = (__bf16)f1.y; t[6] = (__bf16)f1.z; t[7] = (__bf16)f1.w;
        a[kk] = t;
    }

    const bf16x8* wv = reinterpret_cast<const bf16x8*>(wl);
    f32x4 acc[8];
#pragma unroll
    for (int n = 0; n < 8; ++n) acc[n] = (f32x4){0.f, 0.f, 0.f, 0.f};

#pragma unroll
    for (int n = 0; n < 8; ++n) {
#pragma unroll
        for (int kk = 0; kk < 4; ++kk) {
            acc[n] = __builtin_amdgcn_mfma_f32_16x16x32_bf16(
                a[kk], wv[(n * 4 + kk) * 64 + lane], acc[n], 0, 0, 0);
        }
    }

    // C/D layout: col = lane&15, row = (lane>>4)*4 + reg
    int rowbase = blockIdx.x * 64 + wave * 16 + g * 4;
#pragma unroll
    for (int n = 0; n < 8; ++n) {
#pragma unroll
        for (int q = 0; q < 4; ++q) {
            int rr = rowbase + q;
            if (rr < M) H[(size_t)rr * 128 + n * 16 + m15] = (__bf16)acc[n][q];
        }
    }
}

// counts[rel][d] += 1 for both relations of this phase (counts pre-zeroed)
__global__ __launch_bounds__(256) void hist_kernel(const int* __restrict__ dstA,
                                                   const int* __restrict__ dstB,
                                                   int* __restrict__ counts) {
    int i = blockIdx.x * 256 + threadIdx.x;  // 0 .. 2E-1
    int rel = i >= NEDGE;
    int e = i - rel * NEDGE;
    int d = rel ? dstB[e] : dstA[e];
    atomicAdd(&counts[rel * CS + d], 1);
}

// Exclusive scan of counts -> indptr (N+1 entries) and cursor copy. 1 block/rel.
__global__ __launch_bounds__(1024) void scan_kernel(const int* __restrict__ counts,
                                                    int* __restrict__ indptr,
                                                    int* __restrict__ cursor) {
    const int* c = counts + blockIdx.x * CS;
    int* ip = indptr + blockIdx.x * CS;
    int* cur = cursor + blockIdx.x * CS;
    __shared__ int sums[1024];
    int t = threadIdx.x;
    const int C = 49;  // ceil(50000/1024)
    int beg = t * C;
    int end = beg + C < N_NODES ? beg + C : N_NODES;
    int s = 0;
    for (int i = beg; i < end; ++i) s += c[i];
    sums[t] = s;
    __syncthreads();
    // inclusive Hillis-Steele scan
    for (int off = 1; off < 1024; off <<= 1) {
        int v = 0;
        if (t >= off) v = sums[t - off];
        __syncthreads();
        sums[t] += v;
        __syncthreads();
    }
    int excl = (t == 0) ? 0 : sums[t - 1];
    for (int i = beg; i < end; ++i) {
        ip[i] = excl;
        cur[i] = excl;
        excl += c[i];
    }
    if (t == 1023) ip[N_NODES] = sums[1023];  // == E
}

// srcids[rel][pos] = src  with pos = cursor[rel][dst]++
__global__ __launch_bounds__(256) void fill_kernel(const int* __restrict__ srcA,
                                                   const int* __restrict__ dstA,
                                                   const int* __restrict__ srcB,
                                                   const int* __restrict__ dstB,
                                                   int* __restrict__ cursor,
                                                   int* __restrict__ srcids) {
    int i = blockIdx.x * 256 + threadIdx.x;  // 0 .. 2E-1
    int rel = i >= NEDGE;
    int e = i - rel * NEDGE;
    int d = rel ? dstB[e] : dstA[e];
    int s = rel ? srcB[e] : srcA[e];
    int pos = atomicAdd(&cursor[rel * CS + d], 1);
    srcids[rel * NEDGE + pos] = s;
}

// One wave per dst node: out[node] = bias + sum_{e in CSR0} HA[src] + sum_{e in CSR1} HB[src]
__global__ __launch_bounds__(256) void aggregate_kernel(const __bf16* __restrict__ HA,
                                                        const __bf16* __restrict__ HB,
                                                        const int* __restrict__ indptr,
                                                        const int* __restrict__ srcids,
                                                        const float* __restrict__ bias,
                                                        float* __restrict__ out) {
    int idx = blockIdx.x * 256 + threadIdx.x;
    int node = idx >> 6;
    int lane = idx & 63;
    float acc0 = bias[2 * lane];
    float acc1 = bias[2 * lane + 1];
#pragma unroll
    for (int rel = 0; rel < 2; ++rel) {
        const unsigned int* H = reinterpret_cast<const unsigned int*>(rel ? HB : HA);
        int beg = indptr[rel * CS + node];
        int end = indptr[rel * CS + node + 1];
        const int* sp = srcids + rel * NEDGE;
        for (int e = beg; e < end; ++e) {
            int s = sp[e];
            unsigned int hv = H[(size_t)s * 64 + lane];
            union { unsigned int u; float f; } lo, hi;
            lo.u = hv << 16;
            hi.u = hv & 0xFFFF0000u;
            acc0 += lo.f;
            acc1 += hi.f;
        }
    }
    *reinterpret_cast<float2*>(out + (size_t)node * 128 + 2 * lane) =
        make_float2(acc0, acc1);
}

extern "C" void kernel_launch(void* const* d_in, const int* in_sizes, int n_in,
                              void* d_out, int out_size, void* d_ws, size_t ws_size,
                              hipStream_t stream) {
    const float* x0     = (const float*)d_in[0];
    const float* x1     = (const float*)d_in[1];
    const float* weight = (const float*)d_in[2];
    const float* wcomp  = (const float*)d_in[3];
    const float* bias   = (const float*)d_in[4];
    const int* src[4] = {(const int*)d_in[5], (const int*)d_in[7],
                         (const int*)d_in[9], (const int*)d_in[11]};
    const int* dst[4] = {(const int*)d_in[6], (const int*)d_in[8],
                         (const int*)d_in[10], (const int*)d_in[12]};
    float* out = (float*)d_out;

    char* ws = (char*)d_ws;
    __bf16* wfrag = (__bf16*)(ws + OFF_WFRAG);
    __bf16* HA    = (__bf16*)(ws + OFF_HA);
    __bf16* HB    = (__bf16*)(ws + OFF_HB);
    int* counts   = (int*)(ws + OFF_CNT);
    int* indptr   = (int*)(ws + OFF_IPTR);
    int* cursor   = (int*)(ws + OFF_CUR);
    int* srcids   = (int*)(ws + OFF_SRC);

    wfrag_kernel<<<256, 256, 0, stream>>>(weight, wcomp, wfrag);

    // phase p: dst ntype p; relations (p, p+2): src x0 -> HA, src x1 -> HB
    for (int p = 0; p < 2; ++p) {
        int rA = p;        // src ntype 0
        int rB = p + 2;    // src ntype 1
        gemm_kernel<<<(N_NODES + 63) / 64, 256, 0, stream>>>(
            x0, wfrag + rA * 16384, HA, N_NODES);
        gemm_kernel<<<(N_NODES + 63) / 64, 256, 0, stream>>>(
            x1, wfrag + rB * 16384, HB, N_NODES);
        hipMemsetAsync(counts, 0, (size_t)2 * CS * 4, stream);
        hist_kernel<<<2 * NEDGE / 256, 256, 0, stream>>>(dst[rA], dst[rB], counts);
        scan_kernel<<<2, 1024, 0, stream>>>(counts, indptr, cursor);
        fill_kernel<<<2 * NEDGE / 256, 256, 0, stream>>>(
            src[rA], dst[rA], src[rB], dst[rB], cursor, srcids);
        aggregate_kernel<<<N_NODES * 64 / 256, 256, 0, stream>>>(
            HA, HB, indptr, srcids, bias, out + (size_t)p * N_NODES * 128);
    }
}

// Round 3
// 194.688 us; speedup vs baseline: 3.0041x; 2.1185x over previous
//
#include <hip/hip_runtime.h>
#include <hip/hip_bf16.h>

typedef __bf16 bf16x8 __attribute__((ext_vector_type(8)));
typedef float f32x4 __attribute__((ext_vector_type(4)));

#define N_NODES 50000
#define NEDGE 160000
#define CS 50176            // 49 * 1024, padded stride for per-rel count/indptr arrays
#define BLKS_PER_REL 49

// ---- workspace layout (bytes) ----
constexpr size_t OFF_WFRAG = 0;                                   // 131072
constexpr size_t OFF_HA    = 131072;                              // 12.8 MB
constexpr size_t OFF_HB    = OFF_HA + 12800000;                   // 12.8 MB
constexpr size_t OFF_CNT   = OFF_HB + 12800000;                   // 4*CS*4
constexpr size_t OFF_IPTR  = OFF_CNT + (size_t)4 * CS * 4;
constexpr size_t OFF_CUR   = OFF_IPTR + (size_t)4 * CS * 4;
constexpr size_t OFF_PART  = OFF_CUR + (size_t)4 * CS * 4;        // 196*4
constexpr size_t OFF_SRC   = OFF_PART + 1024;                     // 4*E*4

// Compose W[r] = w_comp[r,0]*weight[0] + w_comp[r,1]*weight[1], store bf16 in
// MFMA B-fragment order: offset = (((r*8+n)*4+kk)*64+lane)*8 + j
// where element = W[r][k][o], k = kk*32 + (lane>>4)*8 + j, o = n*16 + (lane&15)
__global__ __launch_bounds__(256) void wfrag_kernel(const float* __restrict__ weight,
                                                    const float* __restrict__ wcomp,
                                                    __bf16* __restrict__ wfrag) {
    int tid = blockIdx.x * 256 + threadIdx.x;  // 65536 total
    int j    = tid & 7;
    int lane = (tid >> 3) & 63;
    int kk   = (tid >> 9) & 3;
    int n    = (tid >> 11) & 7;
    int r    = tid >> 14;
    int k = kk * 32 + ((lane >> 4) << 3) + j;
    int o = (n << 4) + (lane & 15);
    float v = wcomp[r * 2] * weight[k * 128 + o] +
              wcomp[r * 2 + 1] * weight[16384 + k * 128 + o];
    wfrag[tid] = (__bf16)v;
}

// H = x @ W_r  (M x 128, K=128), bf16 output. Block = 4 waves, 64 rows/block.
__global__ __launch_bounds__(256) void gemm_kernel(const float* __restrict__ x,
                                                   const __bf16* __restrict__ wfrag,
                                                   __bf16* __restrict__ H, int M) {
    __shared__ __bf16 wl[16384];  // 32 KB: [n][kk][lane][8]
    {
        const uint4* s = reinterpret_cast<const uint4*>(wfrag);
        uint4* d = reinterpret_cast<uint4*>(wl);
        int t = threadIdx.x;
#pragma unroll
        for (int i = 0; i < 8; ++i) d[t + i * 256] = s[t + i * 256];
    }
    __syncthreads();

    const int lane = threadIdx.x & 63;
    const int wave = threadIdx.x >> 6;
    const int g = lane >> 4;
    const int m15 = lane & 15;

    int row = blockIdx.x * 64 + wave * 16 + m15;
    int rowc = row < M ? row : M - 1;
    const float* xr = x + (size_t)rowc * 128 + g * 8;

    bf16x8 a[4];
#pragma unroll
    for (int kk = 0; kk < 4; ++kk) {
        float4 f0 = *reinterpret_cast<const float4*>(xr + kk * 32);
        float4 f1 = *reinterpret_cast<const float4*>(xr + kk * 32 + 4);
        bf16x8 t;
        t[0] = (__bf16)f0.x; t[1] = (__bf16)f0.y; t[2] = (__bf16)f0.z; t[3] = (__bf16)f0.w;
        t[4] = (__bf16)f1.x; t[5] = (__bf16)f1.y; t[6] = (__bf16)f1.z; t[7] = (__bf16)f1.w;
        a[kk] = t;
    }

    const bf16x8* wv = reinterpret_cast<const bf16x8*>(wl);
    f32x4 acc[8];
#pragma unroll
    for (int n = 0; n < 8; ++n) acc[n] = (f32x4){0.f, 0.f, 0.f, 0.f};

#pragma unroll
    for (int n = 0; n < 8; ++n) {
#pragma unroll
        for (int kk = 0; kk < 4; ++kk) {
            acc[n] = __builtin_amdgcn_mfma_f32_16x16x32_bf16(
                a[kk], wv[(n * 4 + kk) * 64 + lane], acc[n], 0, 0, 0);
        }
    }

    int rowbase = blockIdx.x * 64 + wave * 16 + g * 4;
#pragma unroll
    for (int n = 0; n < 8; ++n) {
#pragma unroll
        for (int q = 0; q < 4; ++q) {
            int rr = rowbase + q;
            if (rr < M) H[(size_t)rr * 128 + n * 16 + m15] = (__bf16)acc[n][q];
        }
    }
}

// counts[rel][d] += 1 for all 4 relations (counts pre-zeroed). i in [0, 4E).
__global__ __launch_bounds__(256) void hist4_kernel(const int* __restrict__ d0,
                                                    const int* __restrict__ d1,
                                                    const int* __restrict__ d2,
                                                    const int* __restrict__ d3,
                                                    int* __restrict__ counts) {
    int i = blockIdx.x * 256 + threadIdx.x;
    int rel = i / NEDGE;
    int e = i - rel * NEDGE;
    const int* dp = rel == 0 ? d0 : rel == 1 ? d1 : rel == 2 ? d2 : d3;
    atomicAdd(&counts[rel * CS + dp[e]], 1);
}

// Per-block partial sums: 49 blocks/rel, 1024 counts/block (int4 per thread).
__global__ __launch_bounds__(256) void block_sums_kernel(const int* __restrict__ counts,
                                                         int* __restrict__ partials) {
    int rel = blockIdx.x / BLKS_PER_REL;
    int blk = blockIdx.x - rel * BLKS_PER_REL;
    const int4* base = reinterpret_cast<const int4*>(counts + rel * CS) + blk * 256;
    int4 v = base[threadIdx.x];
    int s = v.x + v.y + v.z + v.w;
#pragma unroll
    for (int d = 1; d < 64; d <<= 1) s += __shfl_xor(s, d, 64);
    __shared__ int wsum[4];
    int wave = threadIdx.x >> 6;
    int lane = threadIdx.x & 63;
    if (lane == 0) wsum[wave] = s;
    __syncthreads();
    if (threadIdx.x == 0)
        partials[blockIdx.x] = wsum[0] + wsum[1] + wsum[2] + wsum[3];
}

// Exclusive scan + write indptr and cursor (int4 stores).
__global__ __launch_bounds__(256) void scan_write_kernel(const int* __restrict__ counts,
                                                         const int* __restrict__ partials,
                                                         int* __restrict__ indptr,
                                                         int* __restrict__ cursor) {
    int rel = blockIdx.x / BLKS_PER_REL;
    int blk = blockIdx.x - rel * BLKS_PER_REL;
    int lane = threadIdx.x & 63;
    int wave = threadIdx.x >> 6;

    // block offset within this relation: sum of preceding block partials
    int pv = (lane < blk) ? partials[rel * BLKS_PER_REL + lane] : 0;
#pragma unroll
    for (int d = 1; d < 64; d <<= 1) pv += __shfl_xor(pv, d, 64);

    const int4* base = reinterpret_cast<const int4*>(counts + rel * CS) + blk * 256;
    int4 v = base[threadIdx.x];
    int ts = v.x + v.y + v.z + v.w;

    // wave-level inclusive scan of thread sums
    int s = ts;
#pragma unroll
    for (int d = 1; d < 64; d <<= 1) {
        int n = __shfl_up(s, d, 64);
        if (lane >= d) s += n;
    }
    int exclw = s - ts;

    __shared__ int wtot[4];
    if (lane == 63) wtot[wave] = s;
    __syncthreads();
    int woff = 0;
    if (wave > 0) woff += wtot[0];
    if (wave > 1) woff += wtot[1];
    if (wave > 2) woff += wtot[2];

    int e0 = pv + woff + exclw;
    int4 ip;
    ip.x = e0;
    ip.y = e0 + v.x;
    ip.z = ip.y + v.y;
    ip.w = ip.z + v.z;
    reinterpret_cast<int4*>(indptr + rel * CS)[blk * 256 + threadIdx.x] = ip;
    reinterpret_cast<int4*>(cursor + rel * CS)[blk * 256 + threadIdx.x] = ip;
}

// srcids[rel][pos] = src with pos = cursor[rel][dst]++, all 4 relations
__global__ __launch_bounds__(256) void fill4_kernel(const int* __restrict__ s0, const int* __restrict__ d0,
                                                    const int* __restrict__ s1, const int* __restrict__ d1,
                                                    const int* __restrict__ s2, const int* __restrict__ d2,
                                                    const int* __restrict__ s3, const int* __restrict__ d3,
                                                    int* __restrict__ cursor,
                                                    int* __restrict__ srcids) {
    int i = blockIdx.x * 256 + threadIdx.x;
    int rel = i / NEDGE;
    int e = i - rel * NEDGE;
    const int* dp = rel == 0 ? d0 : rel == 1 ? d1 : rel == 2 ? d2 : d3;
    const int* sp = rel == 0 ? s0 : rel == 1 ? s1 : rel == 2 ? s2 : s3;
    int d = dp[e];
    int s = sp[e];
    int pos = atomicAdd(&cursor[rel * CS + d], 1);
    srcids[rel * NEDGE + pos] = s;
}

// One wave per dst node: out[node] = bias + sum HA[srcA] + sum HB[srcB]
__global__ __launch_bounds__(256) void aggregate_kernel(const __bf16* __restrict__ HA,
                                                        const __bf16* __restrict__ HB,
                                                        const int* __restrict__ ipA,
                                                        const int* __restrict__ ipB,
                                                        const int* __restrict__ sidA,
                                                        const int* __restrict__ sidB,
                                                        const float* __restrict__ bias,
                                                        float* __restrict__ out) {
    int idx = blockIdx.x * 256 + threadIdx.x;
    int node = idx >> 6;
    int lane = idx & 63;
    float acc0 = bias[2 * lane];
    float acc1 = bias[2 * lane + 1];
#pragma unroll
    for (int rel = 0; rel < 2; ++rel) {
        const unsigned int* H = reinterpret_cast<const unsigned int*>(rel ? HB : HA);
        const int* ip = rel ? ipB : ipA;
        const int* sp = rel ? sidB : sidA;
        int beg = ip[node];
        int end = ip[node + 1];
        for (int e = beg; e < end; ++e) {
            int s = sp[e];
            unsigned int hv = H[(size_t)s * 64 + lane];
            union { unsigned int u; float f; } lo, hi;
            lo.u = hv << 16;
            hi.u = hv & 0xFFFF0000u;
            acc0 += lo.f;
            acc1 += hi.f;
        }
    }
    *reinterpret_cast<float2*>(out + (size_t)node * 128 + 2 * lane) =
        make_float2(acc0, acc1);
}

extern "C" void kernel_launch(void* const* d_in, const int* in_sizes, int n_in,
                              void* d_out, int out_size, void* d_ws, size_t ws_size,
                              hipStream_t stream) {
    const float* x0     = (const float*)d_in[0];
    const float* x1     = (const float*)d_in[1];
    const float* weight = (const float*)d_in[2];
    const float* wcomp  = (const float*)d_in[3];
    const float* bias   = (const float*)d_in[4];
    const int* src[4] = {(const int*)d_in[5], (const int*)d_in[7],
                         (const int*)d_in[9], (const int*)d_in[11]};
    const int* dst[4] = {(const int*)d_in[6], (const int*)d_in[8],
                         (const int*)d_in[10], (const int*)d_in[12]};
    float* out = (float*)d_out;

    char* ws = (char*)d_ws;
    __bf16* wfrag = (__bf16*)(ws + OFF_WFRAG);
    __bf16* HA    = (__bf16*)(ws + OFF_HA);
    __bf16* HB    = (__bf16*)(ws + OFF_HB);
    int* counts   = (int*)(ws + OFF_CNT);
    int* indptr   = (int*)(ws + OFF_IPTR);
    int* cursor   = (int*)(ws + OFF_CUR);
    int* partials = (int*)(ws + OFF_PART);
    int* srcids   = (int*)(ws + OFF_SRC);

    wfrag_kernel<<<256, 256, 0, stream>>>(weight, wcomp, wfrag);

    // ---- CSR build for all 4 relations ----
    hipMemsetAsync(counts, 0, (size_t)4 * CS * 4, stream);
    hist4_kernel<<<4 * NEDGE / 256, 256, 0, stream>>>(
        dst[0], dst[1], dst[2], dst[3], counts);
    block_sums_kernel<<<4 * BLKS_PER_REL, 256, 0, stream>>>(counts, partials);
    scan_write_kernel<<<4 * BLKS_PER_REL, 256, 0, stream>>>(counts, partials, indptr, cursor);
    fill4_kernel<<<4 * NEDGE / 256, 256, 0, stream>>>(
        src[0], dst[0], src[1], dst[1], src[2], dst[2], src[3], dst[3],
        cursor, srcids);

    // ---- phase p: dst ntype p; relations (p: x0 src, p+2: x1 src) ----
    for (int p = 0; p < 2; ++p) {
        int rA = p;
        int rB = p + 2;
        gemm_kernel<<<(N_NODES + 63) / 64, 256, 0, stream>>>(
            x0, wfrag + rA * 16384, HA, N_NODES);
        gemm_kernel<<<(N_NODES + 63) / 64, 256, 0, stream>>>(
            x1, wfrag + rB * 16384, HB, N_NODES);
        aggregate_kernel<<<N_NODES * 64 / 256, 256, 0, stream>>>(
            HA, HB, indptr + rA * CS, indptr + rB * CS,
            srcids + (size_t)rA * NEDGE, srcids + (size_t)rB * NEDGE,
            bias, out + (size_t)p * N_NODES * 128);
    }
}

// Round 4
// 136.087 us; speedup vs baseline: 4.2977x; 1.4306x over previous
//
#include <hip/hip_runtime.h>
#include <hip/hip_bf16.h>

typedef __bf16 bf16x8 __attribute__((ext_vector_type(8)));
typedef float f32x4 __attribute__((ext_vector_type(4)));

#define N_NODES 50000
#define NEDGE 160000
#define CS 50176            // 49 * 1024, padded stride for per-rel count/indptr arrays
#define BLKS_PER_REL 49
#define HSZ ((size_t)N_NODES * 128)

// ---- workspace layout (bytes) ----
constexpr size_t OFF_WFRAG = 0;                                   // 131072
constexpr size_t OFF_H     = 131072;                              // 4 * 12.8 MB
constexpr size_t OFF_CNT   = OFF_H + 4 * 12800000;                // 4*CS*4
constexpr size_t OFF_IPTR  = OFF_CNT + (size_t)4 * CS * 4;
constexpr size_t OFF_CUR   = OFF_IPTR + (size_t)4 * CS * 4;
constexpr size_t OFF_PART  = OFF_CUR + (size_t)4 * CS * 4;        // 196*4
constexpr size_t OFF_SRC   = OFF_PART + 1024;                     // 4*E*4

// Compose W[r] = w_comp[r,0]*weight[0] + w_comp[r,1]*weight[1], store bf16 in
// MFMA B-fragment order: offset = (((r*8+n)*4+kk)*64+lane)*8 + j
// where element = W[r][k][o], k = kk*32 + (lane>>4)*8 + j, o = n*16 + (lane&15)
__global__ __launch_bounds__(256) void wfrag_kernel(const float* __restrict__ weight,
                                                    const float* __restrict__ wcomp,
                                                    __bf16* __restrict__ wfrag) {
    int tid = blockIdx.x * 256 + threadIdx.x;  // 65536 total
    int j    = tid & 7;
    int lane = (tid >> 3) & 63;
    int kk   = (tid >> 9) & 3;
    int n    = (tid >> 11) & 7;
    int r    = tid >> 14;
    int k = kk * 32 + ((lane >> 4) << 3) + j;
    int o = (n << 4) + (lane & 15);
    float v = wcomp[r * 2] * weight[k * 128 + o] +
              wcomp[r * 2 + 1] * weight[16384 + k * 128 + o];
    wfrag[tid] = (__bf16)v;
}

// H[2y+rr] = x_y @ W_{2y+rr} for rr in {0,1}. A-fragments loaded once per block.
__global__ __launch_bounds__(256) void gemm2_kernel(const float* __restrict__ x0,
                                                    const float* __restrict__ x1,
                                                    const __bf16* __restrict__ wfrag,
                                                    __bf16* __restrict__ Hbase, int M) {
    __shared__ __bf16 wl[16384];  // 32 KB: [n][kk][lane][8]
    const int y = blockIdx.y;     // src ntype
    const float* x = y ? x1 : x0;

    const int lane = threadIdx.x & 63;
    const int wave = threadIdx.x >> 6;
    const int g = lane >> 4;
    const int m15 = lane & 15;

    int row = blockIdx.x * 64 + wave * 16 + m15;
    int rowc = row < M ? row : M - 1;
    const float* xr = x + (size_t)rowc * 128 + g * 8;

    bf16x8 a[4];
#pragma unroll
    for (int kk = 0; kk < 4; ++kk) {
        float4 f0 = *reinterpret_cast<const float4*>(xr + kk * 32);
        float4 f1 = *reinterpret_cast<const float4*>(xr + kk * 32 + 4);
        bf16x8 t;
        t[0] = (__bf16)f0.x; t[1] = (__bf16)f0.y; t[2] = (__bf16)f0.z; t[3] = (__bf16)f0.w;
        t[4] = (__bf16)f1.x; t[5] = (__bf16)f1.y; t[6] = (__bf16)f1.z; t[7] = (__bf16)f1.w;
        a[kk] = t;
    }

    const bf16x8* wv = reinterpret_cast<const bf16x8*>(wl);
    int rowbase = blockIdx.x * 64 + wave * 16 + g * 4;

#pragma unroll
    for (int rr = 0; rr < 2; ++rr) {
        int rel = 2 * y + rr;
        if (rr) __syncthreads();  // previous compute done reading wl
        {
            const uint4* s = reinterpret_cast<const uint4*>(wfrag + rel * 16384);
            uint4* dsl = reinterpret_cast<uint4*>(wl);
            int t = threadIdx.x;
#pragma unroll
            for (int i = 0; i < 8; ++i) dsl[t + i * 256] = s[t + i * 256];
        }
        __syncthreads();

        f32x4 acc[8];
#pragma unroll
        for (int n = 0; n < 8; ++n) acc[n] = (f32x4){0.f, 0.f, 0.f, 0.f};
#pragma unroll
        for (int n = 0; n < 8; ++n) {
#pragma unroll
            for (int kk = 0; kk < 4; ++kk) {
                acc[n] = __builtin_amdgcn_mfma_f32_16x16x32_bf16(
                    a[kk], wv[(n * 4 + kk) * 64 + lane], acc[n], 0, 0, 0);
            }
        }

        __bf16* H = Hbase + (size_t)rel * HSZ;
#pragma unroll
        for (int n = 0; n < 8; ++n) {
#pragma unroll
            for (int q = 0; q < 4; ++q) {
                int rrow = rowbase + q;
                if (rrow < M) H[(size_t)rrow * 128 + n * 16 + m15] = (__bf16)acc[n][q];
            }
        }
    }
}

// counts[rel][d] += 1 for all 4 relations (counts pre-zeroed). i in [0, 4E).
__global__ __launch_bounds__(256) void hist4_kernel(const int* __restrict__ d0,
                                                    const int* __restrict__ d1,
                                                    const int* __restrict__ d2,
                                                    const int* __restrict__ d3,
                                                    int* __restrict__ counts) {
    int i = blockIdx.x * 256 + threadIdx.x;
    int rel = i / NEDGE;
    int e = i - rel * NEDGE;
    const int* dp = rel == 0 ? d0 : rel == 1 ? d1 : rel == 2 ? d2 : d3;
    atomicAdd(&counts[rel * CS + dp[e]], 1);
}

// Per-block partial sums: 49 blocks/rel, 1024 counts/block (int4 per thread).
__global__ __launch_bounds__(256) void block_sums_kernel(const int* __restrict__ counts,
                                                         int* __restrict__ partials) {
    int rel = blockIdx.x / BLKS_PER_REL;
    int blk = blockIdx.x - rel * BLKS_PER_REL;
    const int4* base = reinterpret_cast<const int4*>(counts + rel * CS) + blk * 256;
    int4 v = base[threadIdx.x];
    int s = v.x + v.y + v.z + v.w;
#pragma unroll
    for (int d = 1; d < 64; d <<= 1) s += __shfl_xor(s, d, 64);
    __shared__ int wsum[4];
    int wave = threadIdx.x >> 6;
    int lane = threadIdx.x & 63;
    if (lane == 0) wsum[wave] = s;
    __syncthreads();
    if (threadIdx.x == 0)
        partials[blockIdx.x] = wsum[0] + wsum[1] + wsum[2] + wsum[3];
}

// Exclusive scan + write indptr and cursor (int4 stores).
__global__ __launch_bounds__(256) void scan_write_kernel(const int* __restrict__ counts,
                                                         const int* __restrict__ partials,
                                                         int* __restrict__ indptr,
                                                         int* __restrict__ cursor) {
    int rel = blockIdx.x / BLKS_PER_REL;
    int blk = blockIdx.x - rel * BLKS_PER_REL;
    int lane = threadIdx.x & 63;
    int wave = threadIdx.x >> 6;

    int pv = (lane < blk) ? partials[rel * BLKS_PER_REL + lane] : 0;
#pragma unroll
    for (int d = 1; d < 64; d <<= 1) pv += __shfl_xor(pv, d, 64);

    const int4* base = reinterpret_cast<const int4*>(counts + rel * CS) + blk * 256;
    int4 v = base[threadIdx.x];
    int ts = v.x + v.y + v.z + v.w;

    int s = ts;
#pragma unroll
    for (int d = 1; d < 64; d <<= 1) {
        int n = __shfl_up(s, d, 64);
        if (lane >= d) s += n;
    }
    int exclw = s - ts;

    __shared__ int wtot[4];
    if (lane == 63) wtot[wave] = s;
    __syncthreads();
    int woff = 0;
    if (wave > 0) woff += wtot[0];
    if (wave > 1) woff += wtot[1];
    if (wave > 2) woff += wtot[2];

    int e0 = pv + woff + exclw;
    int4 ip;
    ip.x = e0;
    ip.y = e0 + v.x;
    ip.z = ip.y + v.y;
    ip.w = ip.z + v.z;
    reinterpret_cast<int4*>(indptr + rel * CS)[blk * 256 + threadIdx.x] = ip;
    reinterpret_cast<int4*>(cursor + rel * CS)[blk * 256 + threadIdx.x] = ip;
}

// srcids[rel][pos] = src with pos = cursor[rel][dst]++, all 4 relations
__global__ __launch_bounds__(256) void fill4_kernel(const int* __restrict__ s0, const int* __restrict__ d0,
                                                    const int* __restrict__ s1, const int* __restrict__ d1,
                                                    const int* __restrict__ s2, const int* __restrict__ d2,
                                                    const int* __restrict__ s3, const int* __restrict__ d3,
                                                    int* __restrict__ cursor,
                                                    int* __restrict__ srcids) {
    int i = blockIdx.x * 256 + threadIdx.x;
    int rel = i / NEDGE;
    int e = i - rel * NEDGE;
    const int* dp = rel == 0 ? d0 : rel == 1 ? d1 : rel == 2 ? d2 : d3;
    const int* sp = rel == 0 ? s0 : rel == 1 ? s1 : rel == 2 ? s2 : s3;
    int d = dp[e];
    int s = sp[e];
    int pos = atomicAdd(&cursor[rel * CS + d], 1);
    srcids[rel * NEDGE + pos] = s;
}

// One wave per dst slot (both ntypes): fused two-relation gather with 4-way MLP unroll.
__global__ __launch_bounds__(256) void aggregate_all_kernel(const __bf16* __restrict__ Hbase,
                                                            const int* __restrict__ indptr,
                                                            const int* __restrict__ srcids,
                                                            const float* __restrict__ bias,
                                                            float* __restrict__ out) {
    int idx = blockIdx.x * 256 + threadIdx.x;
    int slot = idx >> 6;      // 0 .. 2*N_NODES-1
    int lane = idx & 63;
    int p = slot >= N_NODES;  // dst ntype
    int node = slot - p * N_NODES;
    int rA = p, rB = p + 2;

    const unsigned int* HA = reinterpret_cast<const unsigned int*>(Hbase + (size_t)rA * HSZ);
    const unsigned int* HB = reinterpret_cast<const unsigned int*>(Hbase + (size_t)rB * HSZ);

    int begA = indptr[rA * CS + node];
    int dA   = indptr[rA * CS + node + 1] - begA;
    int begB = indptr[rB * CS + node];
    int dB   = indptr[rB * CS + node + 1] - begB;
    int d = dA + dB;
    const int* spA = srcids + (size_t)rA * NEDGE + begA;
    const int* spB = srcids + (size_t)rB * NEDGE + begB;

    float2 bv = *reinterpret_cast<const float2*>(bias + 2 * lane);
    float acc0 = bv.x, acc1 = bv.y;

    for (int i = 0; i < d; i += 4) {
        unsigned int hv[4];
#pragma unroll
        for (int k = 0; k < 4; ++k) {
            int j = i + k;
            int jc = j < d ? j : d - 1;  // clamp -> re-reads last row (L1 hit)
            bool isB = jc >= dA;
            int s = isB ? spB[jc - dA] : spA[jc];
            const unsigned int* Hp = isB ? HB : HA;
            unsigned int v = Hp[(size_t)s * 64 + lane];
            hv[k] = (j < d) ? v : 0u;
        }
#pragma unroll
        for (int k = 0; k < 4; ++k) {
            union { unsigned int u; float f; } lo, hi;
            lo.u = hv[k] << 16;
            hi.u = hv[k] & 0xFFFF0000u;
            acc0 += lo.f;
            acc1 += hi.f;
        }
    }
    *reinterpret_cast<float2*>(out + (size_t)slot * 128 + 2 * lane) =
        make_float2(acc0, acc1);
}

extern "C" void kernel_launch(void* const* d_in, const int* in_sizes, int n_in,
                              void* d_out, int out_size, void* d_ws, size_t ws_size,
                              hipStream_t stream) {
    const float* x0     = (const float*)d_in[0];
    const float* x1     = (const float*)d_in[1];
    const float* weight = (const float*)d_in[2];
    const float* wcomp  = (const float*)d_in[3];
    const float* bias   = (const float*)d_in[4];
    const int* src[4] = {(const int*)d_in[5], (const int*)d_in[7],
                         (const int*)d_in[9], (const int*)d_in[11]};
    const int* dst[4] = {(const int*)d_in[6], (const int*)d_in[8],
                         (const int*)d_in[10], (const int*)d_in[12]};
    float* out = (float*)d_out;

    char* ws = (char*)d_ws;
    __bf16* wfrag = (__bf16*)(ws + OFF_WFRAG);
    __bf16* Hbase = (__bf16*)(ws + OFF_H);
    int* counts   = (int*)(ws + OFF_CNT);
    int* indptr   = (int*)(ws + OFF_IPTR);
    int* cursor   = (int*)(ws + OFF_CUR);
    int* partials = (int*)(ws + OFF_PART);
    int* srcids   = (int*)(ws + OFF_SRC);

    wfrag_kernel<<<256, 256, 0, stream>>>(weight, wcomp, wfrag);

    // ---- CSR build for all 4 relations ----
    hipMemsetAsync(counts, 0, (size_t)4 * CS * 4, stream);
    hist4_kernel<<<4 * NEDGE / 256, 256, 0, stream>>>(
        dst[0], dst[1], dst[2], dst[3], counts);
    block_sums_kernel<<<4 * BLKS_PER_REL, 256, 0, stream>>>(counts, partials);
    scan_write_kernel<<<4 * BLKS_PER_REL, 256, 0, stream>>>(counts, partials, indptr, cursor);
    fill4_kernel<<<4 * NEDGE / 256, 256, 0, stream>>>(
        src[0], dst[0], src[1], dst[1], src[2], dst[2], src[3], dst[3],
        cursor, srcids);

    // ---- all 4 GEMMs in one dispatch ----
    gemm2_kernel<<<dim3((N_NODES + 63) / 64, 2), 256, 0, stream>>>(
        x0, x1, wfrag, Hbase, N_NODES);

    // ---- fused aggregation over both dst ntypes ----
    aggregate_all_kernel<<<2 * N_NODES * 64 / 256, 256, 0, stream>>>(
        Hbase, indptr, srcids, bias, out);
}